// Round 18
// baseline (282.822 us; speedup 1.0000x reference)
//
#include <hip/hip_runtime.h>

#define HF 128
#define CAP 64
#define PSHIFT 17          // window >= N -> single pass
#define BUCKET_BLOCKS 2048 // multiple of 8
#define BKS 68             // padded LDS stride for bucket slice (bank spread)

typedef __attribute__((ext_vector_type(8))) short s16x8;
typedef __attribute__((ext_vector_type(4))) float f32x4;
typedef __attribute__((ext_vector_type(2))) float f32x2;

__device__ __forceinline__ unsigned short f2bf(float f) {
    unsigned u = __float_as_uint(f);
    return (unsigned short)((u + 0x7fff + ((u >> 16) & 1)) >> 16);
}

// ---------------- fp8 e4m3 encode/decode (HW path + sw fallback) ----------------
#if __has_builtin(__builtin_amdgcn_cvt_pk_fp8_f32) && __has_builtin(__builtin_amdgcn_cvt_pk_f32_fp8)
#define FP8_HW 1
#else
#define FP8_HW 0
#endif

__device__ __forceinline__ unsigned char f2fp8(float f) {
#if FP8_HW
    int v = __builtin_amdgcn_cvt_pk_fp8_f32(f, f, 0, false);
    return (unsigned char)(v & 0xff);
#else
    unsigned u = __float_as_uint(f);
    unsigned s = (u >> 24) & 0x80;
    float a = fabsf(f);
    if (a > 448.f) a = 448.f;
    if (a < 0.015625f) {
        int q = (int)(a * 512.f + 0.5f);
        return (unsigned char)(s | q);
    }
    unsigned ub = __float_as_uint(a);
    ub += 0x0007ffff + ((ub >> 20) & 1);
    int e8 = (int)(ub >> 23) - 127 + 7;
    if (e8 >= 16) return (unsigned char)(s | 0x7e);
    return (unsigned char)(s | (e8 << 3) | ((ub >> 20) & 7));
#endif
}

__device__ __forceinline__ void fp8acc4(unsigned w, float* acc) {
#if FP8_HW
    f32x2 lo = __builtin_amdgcn_cvt_pk_f32_fp8(w, false);
    f32x2 hi = __builtin_amdgcn_cvt_pk_f32_fp8(w, true);
    acc[0] += lo.x; acc[1] += lo.y; acc[2] += hi.x; acc[3] += hi.y;
#else
    #pragma unroll
    for (int j = 0; j < 4; ++j) {
        unsigned b = (w >> (8 * j)) & 0xff;
        unsigned s = (b >> 7) & 1, e = (b >> 3) & 15, m = b & 7;
        float v = e ? __uint_as_float(((e + 120) << 23) | (m << 20))
                    : (float)m * 0.001953125f;
        acc[j] += s ? -v : v;
    }
#endif
}

// ---------------- one-launch repack of all weights + uvc fold ----------------
__device__ __forceinline__ void repack_one(
    const float* __restrict__ W, short* __restrict__ Wp, int K, int t)
{
    int nkt = K >> 5;
    int lane = t & 63;
    int kt = (t >> 6) % nkt;
    int nt = (t >> 6) / nkt;
    int c = nt * 16 + (lane & 15);
    int kbase = kt * 32 + (lane >> 4) * 8;
    s16x8 v;
    #pragma unroll
    for (int j = 0; j < 8; ++j) v[j] = (short)f2bf(W[(long)(kbase + j) * HF + c]);
    *(s16x8*)(Wp + (long)t * 8) = v;
}

__global__ __launch_bounds__(256) void repack_all(
    const float* __restrict__ preW, const float* __restrict__ c1Ws,
    const float* __restrict__ c1Wn, const float* __restrict__ c2Ws,
    const float* __restrict__ c2Wn, const float* __restrict__ dW1,
    const float* __restrict__ dW2,
    short* preWp, short* c1Wsp, short* c1Wnp, short* c2Wsp, short* c2Wnp,
    short* dW1p, short* dW2p,
    const float* __restrict__ npW, const float* __restrict__ npb,
    const float* __restrict__ dW3, const float* __restrict__ db3,
    const float* __restrict__ fW,  const float* __restrict__ fb,
    float* __restrict__ uvc)
{
    int b = blockIdx.x;
    if (b == 64) {
        int i = threadIdx.x;
        if (i < HF) {
            float u = 0.f, v = 0.f;
            for (int j = 0; j < HF; ++j) {
                u += npW[i * HF + j] * fW[j];
                v += dW3[i * HF + j] * fW[HF + j];
            }
            uvc[i] = u;
            uvc[HF + i] = v;
            if (i == 0) {
                float c = fb[0];
                for (int j = 0; j < HF; ++j) c += npb[j] * fW[j] + db3[j] * fW[HF + j];
                uvc[2 * HF] = c;
            }
        }
        return;
    }
    if (b < 16) { repack_one(preW, preWp, 256, b * 256 + threadIdx.x); return; }
    int m = (b - 16) >> 3, t = ((b - 16) & 7) * 256 + threadIdx.x;
    const float* W; short* Wp;
    switch (m) {
        case 0: W = c1Ws; Wp = c1Wsp; break;
        case 1: W = c1Wn; Wp = c1Wnp; break;
        case 2: W = c2Ws; Wp = c2Wsp; break;
        case 3: W = c2Wn; Wp = c2Wnp; break;
        case 4: W = dW1;  Wp = dW1p;  break;
        default: W = dW2; Wp = dW2p;  break;
    }
    repack_one(W, Wp, HF, t);
}

// ---------------- bucket build: standalone, XCD-owned lines, single pass ----------
__global__ __launch_bounds__(256) void bucketx_kernel(
    const int* __restrict__ eidx, long E,
    int* __restrict__ deg, int* __restrict__ bucket, int npass)
{
    const int xcd   = blockIdx.x & 7;
    const int chunk = blockIdx.x >> 3;
    const int nchunks = BUCKET_BLOCKS / 8;
    long per = (E + nchunks - 1) / nchunks;
    per = (per + 3) & ~3L;
    const long e0 = (long)chunk * per;
    const long e1 = (e0 + per < E) ? e0 + per : E;
    if (e0 >= E) return;
    for (int p = 0; p < npass; ++p) {
        for (long e = e0 + (long)threadIdx.x * 4; e + 4 <= e1; e += 1024) {
            int4 d4 = *(const int4*)(eidx + E + e);
            #pragma unroll
            for (int j = 0; j < 4; ++j) {
                int d = (&d4.x)[j];
                if ((d >> PSHIFT) != p || ((d >> 4) & 7) != xcd) continue;
                int s = eidx[e + j];
                int pos = atomicAdd(&deg[d], 1);
                if (pos < CAP) bucket[(long)d * CAP + pos] = s;
            }
        }
        for (long e = (e1 & ~3L) + threadIdx.x; e < e1; e += 256) {
            int d = eidx[E + e];
            if ((d >> PSHIFT) != p || ((d >> 4) & 7) != xcd) continue;
            int s = eidx[e];
            int pos = atomicAdd(&deg[d], 1);
            if (pos < CAP) bucket[(long)d * CAP + pos] = s;
        }
    }
}

// ---------------- bucket slice staging: predicated (skip chunks past deg) --------
__device__ __forceinline__ void stage_bucket(
    const int* __restrict__ bucket, const int* __restrict__ deg,
    long row0B, int n, int* ldsbkt, int* ldsdeg)
{
    if (threadIdx.x < 64) {
        long node = row0B + threadIdx.x;
        ldsdeg[threadIdx.x] = (node < n) ? deg[node] : 0;
    }
    const uint4* gb = (const uint4*)(bucket + row0B * CAP);
    #pragma unroll
    for (int h = 0; h < 2; ++h) {
        int u = threadIdx.x + h * 512;
        int row = u >> 4, q = u & 15;
        long node = row0B + row;
        int dgr = (node < n) ? deg[node] : 0;
        if (dgr > CAP) dgr = CAP;
        if (q * 4 < dgr)
            *(uint4*)&ldsbkt[row * BKS + q * 4] = gb[u];
    }
}

// ---------------- agg v2: 8 lanes/row x uint4, LDS indices, 8-deep MLP -----------
__device__ __forceinline__ void agg_tile_v2(
    const unsigned char* __restrict__ hq,
    const int* ldsbkt, const int* ldsdeg,
    int n, long row0B, int wv, int lane, unsigned* ldsagg)
{
    const int r = lane >> 3;
    const int i = lane & 7;
    const int rg = wv * 8 + r;

    const int dg = ldsdeg[rg];
    const int m  = dg < CAP ? dg : CAP;
    int maxm = m;
    maxm = max(maxm, __shfl_xor(maxm, 8, 64));
    maxm = max(maxm, __shfl_xor(maxm, 16, 64));
    maxm = max(maxm, __shfl_xor(maxm, 32, 64));

    float acc[16];
    #pragma unroll
    for (int j = 0; j < 16; ++j) acc[j] = 0.f;

    const int* bl = ldsbkt + rg * BKS;
    for (int e = 0; e < maxm; e += 8) {
        int4 ia = *(const int4*)(bl + e);
        int4 ib = *(const int4*)(bl + e + 4);
        int s0 = (e + 0 < m) ? ia.x : 0;
        int s1 = (e + 1 < m) ? ia.y : 0;
        int s2 = (e + 2 < m) ? ia.z : 0;
        int s3 = (e + 3 < m) ? ia.w : 0;
        int s4 = (e + 4 < m) ? ib.x : 0;
        int s5 = (e + 5 < m) ? ib.y : 0;
        int s6 = (e + 6 < m) ? ib.z : 0;
        int s7 = (e + 7 < m) ? ib.w : 0;
        uint4 v0 = *(const uint4*)(hq + (long)s0 * HF + i * 16);
        uint4 v1 = *(const uint4*)(hq + (long)s1 * HF + i * 16);
        uint4 v2 = *(const uint4*)(hq + (long)s2 * HF + i * 16);
        uint4 v3 = *(const uint4*)(hq + (long)s3 * HF + i * 16);
        uint4 v4 = *(const uint4*)(hq + (long)s4 * HF + i * 16);
        uint4 v5 = *(const uint4*)(hq + (long)s5 * HF + i * 16);
        uint4 v6 = *(const uint4*)(hq + (long)s6 * HF + i * 16);
        uint4 v7 = *(const uint4*)(hq + (long)s7 * HF + i * 16);
        if (e + 0 < m) { fp8acc4(v0.x, acc); fp8acc4(v0.y, acc + 4); fp8acc4(v0.z, acc + 8); fp8acc4(v0.w, acc + 12); }
        if (e + 1 < m) { fp8acc4(v1.x, acc); fp8acc4(v1.y, acc + 4); fp8acc4(v1.z, acc + 8); fp8acc4(v1.w, acc + 12); }
        if (e + 2 < m) { fp8acc4(v2.x, acc); fp8acc4(v2.y, acc + 4); fp8acc4(v2.z, acc + 8); fp8acc4(v2.w, acc + 12); }
        if (e + 3 < m) { fp8acc4(v3.x, acc); fp8acc4(v3.y, acc + 4); fp8acc4(v3.z, acc + 8); fp8acc4(v3.w, acc + 12); }
        if (e + 4 < m) { fp8acc4(v4.x, acc); fp8acc4(v4.y, acc + 4); fp8acc4(v4.z, acc + 8); fp8acc4(v4.w, acc + 12); }
        if (e + 5 < m) { fp8acc4(v5.x, acc); fp8acc4(v5.y, acc + 4); fp8acc4(v5.z, acc + 8); fp8acc4(v5.w, acc + 12); }
        if (e + 6 < m) { fp8acc4(v6.x, acc); fp8acc4(v6.y, acc + 4); fp8acc4(v6.z, acc + 8); fp8acc4(v6.w, acc + 12); }
        if (e + 7 < m) { fp8acc4(v7.x, acc); fp8acc4(v7.y, acc + 4); fp8acc4(v7.z, acc + 8); fp8acc4(v7.w, acc + 12); }
    }

    const float sc = 1.f / (float)(dg > 1 ? dg : 1);
    unsigned pk[8];
    #pragma unroll
    for (int j = 0; j < 8; ++j)
        pk[j] = (unsigned)f2bf(acc[2 * j] * sc) | ((unsigned)f2bf(acc[2 * j + 1] * sc) << 16);
    const int c0 = 2 * i, c1 = 2 * i + 1, s = rg & 15;
    *(uint4*)&ldsagg[rg * 64 + ((c0 ^ s) << 2)] = make_uint4(pk[0], pk[1], pk[2], pk[3]);
    *(uint4*)&ldsagg[rg * 64 + ((c1 ^ s) << 2)] = make_uint4(pk[4], pk[5], pk[6], pk[7]);
}

// ---------------- MFMA GEMM pass, A from global, 4-col-tile (N-split) ----------
__device__ __forceinline__ void gemm_pass4(
    const unsigned short* __restrict__ Av, const short* __restrict__ Wp,
    long rA, int lane, int nb, f32x4 acc[4])
{
    const int q = lane >> 4;
    #pragma unroll
    for (int kt = 0; kt < 4; ++kt) {
        s16x8 a = *(const s16x8*)(Av + rA * HF + kt * 32 + q * 8);
        #pragma unroll
        for (int j = 0; j < 4; ++j) {
            s16x8 b = *(const s16x8*)(Wp + ((long)((nb + j) * 4 + kt) * 64 + lane) * 8);
            acc[j] = __builtin_amdgcn_mfma_f32_16x16x32_bf16(a, b, acc[j], 0, 0, 0);
        }
    }
}

__device__ __forceinline__ void gemm_pass_lds4(
    const unsigned* lds, int w3, int lane, const short* __restrict__ Wp,
    int nb, f32x4 acc[4])
{
    const int q = lane >> 4;
    const int i15 = lane & 15;
    const int rl = w3 * 16 + i15;
    #pragma unroll
    for (int kt = 0; kt < 4; ++kt) {
        s16x8 a = *(const s16x8*)&lds[rl * 64 + (((kt * 4 + q) ^ i15) << 2)];
        #pragma unroll
        for (int j = 0; j < 4; ++j) {
            s16x8 b = *(const s16x8*)(Wp + ((long)((nb + j) * 4 + kt) * 64 + lane) * 8);
            acc[j] = __builtin_amdgcn_mfma_f32_16x16x32_bf16(a, b, acc[j], 0, 0, 0);
        }
    }
}

__device__ __forceinline__ void gemm_pass_mfma8(
    const unsigned short* __restrict__ Av, const short* __restrict__ Wp,
    long rA, int lane, f32x4 acc[8])
{
    const int q = lane >> 4;
    #pragma unroll
    for (int kt = 0; kt < 4; ++kt) {
        s16x8 a = *(const s16x8*)(Av + rA * HF + kt * 32 + q * 8);
        #pragma unroll
        for (int nt = 0; nt < 8; ++nt) {
            s16x8 b = *(const s16x8*)(Wp + ((long)(nt * 4 + kt) * 64 + lane) * 8);
            acc[nt] = __builtin_amdgcn_mfma_f32_16x16x32_bf16(a, b, acc[nt], 0, 0, 0);
        }
    }
}

__device__ __forceinline__ void gemm_pass_lds8(
    const unsigned* lds, int w3, int lane, const short* __restrict__ Wp, f32x4 acc[8])
{
    const int q = lane >> 4;
    const int i15 = lane & 15;
    const int rl = w3 * 16 + i15;
    #pragma unroll
    for (int kt = 0; kt < 4; ++kt) {
        s16x8 a = *(const s16x8*)&lds[rl * 64 + (((kt * 4 + q) ^ i15) << 2)];
        #pragma unroll
        for (int nt = 0; nt < 8; ++nt) {
            s16x8 b = *(const s16x8*)(Wp + ((long)(nt * 4 + kt) * 64 + lane) * 8);
            acc[nt] = __builtin_amdgcn_mfma_f32_16x16x32_bf16(a, b, acc[nt], 0, 0, 0);
        }
    }
}

// ---------------- prekd (512 thr): async x-stage, dist head during stage, -------
//                  8-wave N-split pre-GEMM, packed h0/h0q/y1 epilogue
__global__ __launch_bounds__(512) void prekd_kernel(
    const float* __restrict__ x, const short* __restrict__ preWp,
    const float* __restrict__ preb, unsigned short* __restrict__ h0,
    unsigned char* __restrict__ h0q,
    const float* __restrict__ ea, const float* __restrict__ W0,
    const float* __restrict__ b0, const short* __restrict__ W1p,
    const float* __restrict__ b1, unsigned short* __restrict__ y1, int n)
{
    __shared__ float ldsx[64 * 256];     // 64 KB fp32 tile; reused as pack tiles
    const int lane = threadIdx.x & 63;
    const int wv   = threadIdx.x >> 6;
    const long row0B = (long)blockIdx.x * 64;
    const int w3 = wv & 3;
    const int nb = (wv >> 2) * 4;
    const int q  = lane >> 4;
    const int l15 = lane & 15;
    const int cq = lane >> 4;

    // --- issue async x staging ---
    #pragma unroll
    for (int rr = 0; rr < 8; ++rr) {
        const int row = wv * 8 + rr;
        const long gr = row0B + row;
        if (gr < n) {
            const int s = row & 7;
            const float* gp = x + gr * 256 + ((lane ^ s) << 2);
#if __has_builtin(__builtin_amdgcn_global_load_lds)
            __builtin_amdgcn_global_load_lds(
                (const __attribute__((address_space(1))) void*)gp,
                (__attribute__((address_space(3))) void*)&ldsx[row * 256], 16, 0, 0);
#else
            float4 f = *(const float4*)gp;
            *(float4*)&ldsx[row * 256 + lane * 4] = f;
#endif
        }
    }

    // --- dist head for the same 64 rows (no LDS; overlaps grid-wide with staging) ---
    unsigned py[8];
    {
        long rA = row0B + w3 * 16 + l15;
        if (rA > n - 1) rA = n - 1;
        float e0 = ea[rA * 5 + 0], e1 = ea[rA * 5 + 1], e2 = ea[rA * 5 + 2],
              e3 = ea[rA * 5 + 3], e4 = ea[rA * 5 + 4];

        f32x4 accd[4];
        #pragma unroll
        for (int j = 0; j < 4; ++j)
            #pragma unroll
            for (int i = 0; i < 4; ++i) accd[j][i] = 0.f;

        #pragma unroll
        for (int kt = 0; kt < 4; ++kt) {
            const int c = kt * 32 + q * 8;
            s16x8 a;
            #pragma unroll
            for (int h = 0; h < 2; ++h) {
                float4 w0 = *(const float4*)(W0 + 0 * HF + c + h * 4);
                float4 w1 = *(const float4*)(W0 + 1 * HF + c + h * 4);
                float4 w2 = *(const float4*)(W0 + 2 * HF + c + h * 4);
                float4 w3v = *(const float4*)(W0 + 3 * HF + c + h * 4);
                float4 w4 = *(const float4*)(W0 + 4 * HF + c + h * 4);
                float4 bb = *(const float4*)(b0 + c + h * 4);
                float z0 = fmaxf(bb.x + e0 * w0.x + e1 * w1.x + e2 * w2.x + e3 * w3v.x + e4 * w4.x, 0.f);
                float z1 = fmaxf(bb.y + e0 * w0.y + e1 * w1.y + e2 * w2.y + e3 * w3v.y + e4 * w4.y, 0.f);
                float z2 = fmaxf(bb.z + e0 * w0.z + e1 * w1.z + e2 * w2.z + e3 * w3v.z + e4 * w4.z, 0.f);
                float z3 = fmaxf(bb.w + e0 * w0.w + e1 * w1.w + e2 * w2.w + e3 * w3v.w + e4 * w4.w, 0.f);
                a[h * 4 + 0] = (short)f2bf(z0); a[h * 4 + 1] = (short)f2bf(z1);
                a[h * 4 + 2] = (short)f2bf(z2); a[h * 4 + 3] = (short)f2bf(z3);
            }
            #pragma unroll
            for (int j = 0; j < 4; ++j) {
                s16x8 b = *(const s16x8*)(W1p + ((long)((nb + j) * 4 + kt) * 64 + lane) * 8);
                accd[j] = __builtin_amdgcn_mfma_f32_16x16x32_bf16(a, b, accd[j], 0, 0, 0);
            }
        }
        #pragma unroll
        for (int j = 0; j < 4; ++j) {
            float bs = b1[(nb + j) * 16 + l15];
            unsigned short v0 = f2bf(fmaxf(accd[j][0] + bs, 0.f));
            unsigned short v1 = f2bf(fmaxf(accd[j][1] + bs, 0.f));
            unsigned short v2 = f2bf(fmaxf(accd[j][2] + bs, 0.f));
            unsigned short v3 = f2bf(fmaxf(accd[j][3] + bs, 0.f));
            py[j * 2]     = (unsigned)v0 | ((unsigned)v1 << 16);
            py[j * 2 + 1] = (unsigned)v2 | ((unsigned)v3 << 16);
        }
    }
    __syncthreads();   // x tile ready

    // --- pre GEMM from staged x ---
    const int rl = w3 * 16 + l15;
    const int s  = rl & 7;
    f32x4 acc[4];
    #pragma unroll
    for (int j = 0; j < 4; ++j)
        #pragma unroll
        for (int i = 0; i < 4; ++i) acc[j][i] = 0.f;

    #pragma unroll
    for (int kt = 0; kt < 8; ++kt) {
        const int c0 = kt * 8 + q * 2;
        float4 f0 = *(const float4*)&ldsx[rl * 256 + ((c0 ^ s) << 2)];
        float4 f1 = *(const float4*)&ldsx[rl * 256 + (((c0 + 1) ^ s) << 2)];
        s16x8 a;
        a[0] = (short)f2bf(f0.x); a[1] = (short)f2bf(f0.y);
        a[2] = (short)f2bf(f0.z); a[3] = (short)f2bf(f0.w);
        a[4] = (short)f2bf(f1.x); a[5] = (short)f2bf(f1.y);
        a[6] = (short)f2bf(f1.z); a[7] = (short)f2bf(f1.w);
        #pragma unroll
        for (int j = 0; j < 4; ++j) {
            s16x8 b = *(const s16x8*)(preWp + ((long)((nb + j) * 8 + kt) * 64 + lane) * 8);
            acc[j] = __builtin_amdgcn_mfma_f32_16x16x32_bf16(a, b, acc[j], 0, 0, 0);
        }
    }
    __syncthreads();   // ldsx free for pack tiles

    // --- pack epilogue: h0 bf16 [0,16K), h0q fp8 [16K,24K), y1 bf16 [24K,40K) ---
    unsigned short* lp16  = (unsigned short*)ldsx;
    unsigned char*  lp8   = (unsigned char*)ldsx + 16384;
    unsigned short* lp16y = (unsigned short*)((char*)ldsx + 24576);
    #pragma unroll
    for (int j = 0; j < 4; ++j) {
        int col = (nb + j) * 16 + l15;
        float bs = preb[col];
        #pragma unroll
        for (int i = 0; i < 4; ++i) {
            int row = w3 * 16 + cq * 4 + i;
            float o = acc[j][i] + bs;
            lp16[row * 128 + col] = f2bf(o);
            lp8[row * 128 + col]  = f2fp8(o);
            lp16y[row * 128 + col] = (unsigned short)(py[j * 2 + (i >> 1)] >> ((i & 1) * 16));
        }
    }
    __syncthreads();

    const int r = threadIdx.x >> 3;
    const int c = (threadIdx.x & 7) * 16;
    const long gr = row0B + r;
    if (gr < n) {
        uint4* s16p = (uint4*)&lp16[r * 128 + c];
        *(uint4*)(h0 + gr * HF + c)     = s16p[0];
        *(uint4*)(h0 + gr * HF + c + 8) = s16p[1];
        *(uint4*)(h0q + gr * HF + c)    = *(uint4*)&lp8[r * 128 + c];
        uint4* sy = (uint4*)&lp16y[r * 128 + c];
        *(uint4*)(y1 + gr * HF + c)     = sy[0];
        *(uint4*)(y1 + gr * HF + c + 8) = sy[1];
    }
}

// ---------------- c1f (512 thr): staged-bucket agg, then 8-wave N-split GEMM ------
__global__ __launch_bounds__(512) void c1f_kernel(
    const unsigned short* __restrict__ h0, const unsigned char* __restrict__ h0q,
    const int* __restrict__ deg, const int* __restrict__ bucket,
    const short* __restrict__ Wsp, const short* __restrict__ Wnp,
    const float* __restrict__ bias, unsigned short* __restrict__ out,
    unsigned char* __restrict__ outq, int n)
{
    __shared__ unsigned ldsagg[64 * 64];
    __shared__ int ldsbkt[64 * BKS];
    __shared__ int ldsdeg[64];
    const int lane = threadIdx.x & 63;
    const int wv   = threadIdx.x >> 6;
    const long row0B = (long)blockIdx.x * 64;

    stage_bucket(bucket, deg, row0B, n, ldsbkt, ldsdeg);
    __syncthreads();
    agg_tile_v2(h0q, ldsbkt, ldsdeg, n, row0B, wv, lane, ldsagg);
    __syncthreads();

    const int w3 = wv & 3;
    const int nb = (wv >> 2) * 4;

    f32x4 acc[4];
    #pragma unroll
    for (int j = 0; j < 4; ++j)
        #pragma unroll
        for (int i = 0; i < 4; ++i) acc[j][i] = 0.f;

    const long row0 = row0B + w3 * 16;
    long rA = row0 + (lane & 15);
    if (rA > n - 1) rA = n - 1;

    gemm_pass4(h0, Wsp, rA, lane, nb, acc);
    gemm_pass_lds4(ldsagg, w3, lane, Wnp, nb, acc);

    const int cq = lane >> 4;
    #pragma unroll
    for (int j = 0; j < 4; ++j) {
        int col = (nb + j) * 16 + (lane & 15);
        float bs = bias[col];
        #pragma unroll
        for (int i = 0; i < 4; ++i) {
            long r = row0 + cq * 4 + i;
            if (r < n) {
                float o = fmaxf(acc[j][i] + bs, 0.f);
                out[r * HF + col] = f2bf(o);
                outq[r * HF + col] = f2fp8(o);
            }
        }
    }
}

// ---------------- tailf (512 thr): staged-bucket agg; h waves 0-3 || y waves 4-7 --
__global__ __launch_bounds__(512) void tailf_kernel(
    const unsigned short* __restrict__ h1, const unsigned char* __restrict__ h1q,
    const unsigned short* __restrict__ y1,
    const int* __restrict__ deg, const int* __restrict__ bucket,
    const short* __restrict__ c2Wsp, const short* __restrict__ c2Wnp,
    const short* __restrict__ dW2p,
    const float* __restrict__ c2b, const float* __restrict__ db2,
    const float* __restrict__ uvc, float* __restrict__ out, int n)
{
    __shared__ unsigned ldsagg[64 * 64];
    __shared__ int ldsbkt[64 * BKS];
    __shared__ int ldsdeg[64];
    __shared__ float pp[2][64];
    const int lane = threadIdx.x & 63;
    const int wv   = threadIdx.x >> 6;
    const long row0B = (long)blockIdx.x * 64;

    stage_bucket(bucket, deg, row0B, n, ldsbkt, ldsdeg);
    __syncthreads();
    agg_tile_v2(h1q, ldsbkt, ldsdeg, n, row0B, wv, lane, ldsagg);
    __syncthreads();

    const int w = wv & 3;
    const long row0 = row0B + w * 16;
    long rA = row0 + (lane & 15);
    if (rA > n - 1) rA = n - 1;
    const int cq = lane >> 4;
    float part[4] = {0.f, 0.f, 0.f, 0.f};

    f32x4 acc[8];
    #pragma unroll
    for (int nt = 0; nt < 8; ++nt)
        #pragma unroll
        for (int i = 0; i < 4; ++i) acc[nt][i] = 0.f;

    if (wv < 4) {
        gemm_pass_mfma8(h1, c2Wsp, rA, lane, acc);
        gemm_pass_lds8(ldsagg, w, lane, c2Wnp, acc);
        #pragma unroll
        for (int nt = 0; nt < 8; ++nt) {
            int col = nt * 16 + (lane & 15);
            float bh = c2b[col], uu = uvc[col];
            #pragma unroll
            for (int i = 0; i < 4; ++i)
                part[i] += fmaxf(acc[nt][i] + bh, 0.f) * uu;
        }
    } else {
        gemm_pass_mfma8(y1, dW2p, rA, lane, acc);
        #pragma unroll
        for (int nt = 0; nt < 8; ++nt) {
            int col = nt * 16 + (lane & 15);
            float by = db2[col], vv = uvc[HF + col];
            #pragma unroll
            for (int i = 0; i < 4; ++i)
                part[i] += fmaxf(acc[nt][i] + by, 0.f) * vv;
        }
    }

    #pragma unroll
    for (int i = 0; i < 4; ++i) {
        float s = part[i];
        s += __shfl_xor(s, 1, 64);
        s += __shfl_xor(s, 2, 64);
        s += __shfl_xor(s, 4, 64);
        s += __shfl_xor(s, 8, 64);
        part[i] = s;
    }
    if ((lane & 15) == 0) {
        #pragma unroll
        for (int i = 0; i < 4; ++i)
            pp[wv >> 2][w * 16 + cq * 4 + i] = part[i];
    }
    __syncthreads();

    if (threadIdx.x < 64) {
        long r = row0B + threadIdx.x;
        if (r < n) {
            float s = pp[0][threadIdx.x] + pp[1][threadIdx.x] + uvc[2 * HF];
            out[r] = 1.f / (1.f + expf(-s));
        }
    }
}

extern "C" void kernel_launch(void* const* d_in, const int* in_sizes, int n_in,
                              void* d_out, int out_size, void* d_ws, size_t ws_size,
                              hipStream_t stream)
{
    const float* x      = (const float*)d_in[0];
    const int*   eidx   = (const int*)  d_in[1];
    const float* eattr  = (const float*)d_in[2];
    const float* pre_W  = (const float*)d_in[3];
    const float* pre_b  = (const float*)d_in[4];
    const float* c1_Ws  = (const float*)d_in[5];
    const float* c1_Wn  = (const float*)d_in[6];
    const float* c1_b   = (const float*)d_in[7];
    const float* c2_Ws  = (const float*)d_in[8];
    const float* c2_Wn  = (const float*)d_in[9];
    const float* c2_b   = (const float*)d_in[10];
    const float* npW    = (const float*)d_in[11];
    const float* npb    = (const float*)d_in[12];
    const float* dW0    = (const float*)d_in[13];
    const float* db0    = (const float*)d_in[14];
    const float* dW1    = (const float*)d_in[15];
    const float* db1    = (const float*)d_in[16];
    const float* dW2    = (const float*)d_in[17];
    const float* db2    = (const float*)d_in[18];
    const float* dW3    = (const float*)d_in[19];
    const float* db3    = (const float*)d_in[20];
    const float* fW     = (const float*)d_in[21];
    const float* fb     = (const float*)d_in[22];

    const int  n = in_sizes[0] / 256;
    const long E = in_sizes[1] / 2;

    char* ws = (char*)d_ws;
    size_t off = 0;
    auto alloc = [&](size_t bytes) -> void* {
        void* p = ws + off;
        off += (bytes + 255) & ~(size_t)255;
        return p;
    };
    unsigned short* B0 = (unsigned short*)alloc((size_t)n * HF * 2); // h0
    unsigned short* B1 = (unsigned short*)alloc((size_t)n * HF * 2); // h1
    unsigned short* B2 = (unsigned short*)alloc((size_t)n * HF * 2); // y1
    unsigned char*  B0q = (unsigned char*)alloc((size_t)n * HF);    // h0 fp8
    unsigned char*  B1q = (unsigned char*)alloc((size_t)n * HF);    // h1 fp8
    int*   deg    = (int*)alloc((size_t)n * sizeof(int));
    int*   bucket = (int*)alloc(((size_t)n + 64) * CAP * sizeof(int));
    float* uvc    = (float*)alloc((2 * HF + 1) * sizeof(float));
    short* preWp  = (short*)alloc(256 * HF * 2);
    short* c1Wsp  = (short*)alloc(HF * HF * 2);
    short* c1Wnp  = (short*)alloc(HF * HF * 2);
    short* c2Wsp  = (short*)alloc(HF * HF * 2);
    short* c2Wnp  = (short*)alloc(HF * HF * 2);
    short* dW1p   = (short*)alloc(HF * HF * 2);
    short* dW2p   = (short*)alloc(HF * HF * 2);

    const int gemmBlocks = (n + 63) / 64;
    const int npass = ((n - 1) >> PSHIFT) + 1;   // 1 at N=100k

    repack_all<<<65, 256, 0, stream>>>(
        pre_W, c1_Ws, c1_Wn, c2_Ws, c2_Wn, dW1, dW2,
        preWp, c1Wsp, c1Wnp, c2Wsp, c2Wnp, dW1p, dW2p,
        npW, npb, dW3, db3, fW, fb, uvc);

    hipMemsetAsync(deg, 0, (size_t)n * sizeof(int), stream);

    // bucket build: standalone XCD-owned binned scatter (proven floor)
    bucketx_kernel<<<BUCKET_BLOCKS, 256, 0, stream>>>(eidx, E, deg, bucket, npass);

    // h0 = x @ pre_W + pre_b with dist head fused (computed during x staging)
    prekd_kernel<<<gemmBlocks, 512, 0, stream>>>(
        x, preWp, pre_b, B0, B0q,
        eattr, dW0, db0, dW1p, db1, B2, n);

    // h1 = relu(h0@c1Ws + agg1@c1Wn + b): predicated-staged indices + wide gather
    c1f_kernel<<<gemmBlocks, 512, 0, stream>>>(
        B0, B0q, deg, bucket, c1Wsp, c1Wnp, c1_b, B1, B1q, n);

    // tail: staged agg2 + parallel h/y GEMM paths + final dot + sigmoid
    tailf_kernel<<<gemmBlocks, 512, 0, stream>>>(
        B1, B1q, B2, deg, bucket, c2Wsp, c2Wnp, dW2p, c2_b, db2, uvc, (float*)d_out, n);
}

// Round 19
// 268.444 us; speedup vs baseline: 1.0536x; 1.0536x over previous
//
#include <hip/hip_runtime.h>

#define HF 128
#define CAP 64
#define PSHIFT 17          // window >= N -> single pass
#define BUCKET_BLOCKS 2048 // multiple of 8
#define BKS 68             // padded LDS stride for bucket slice (bank spread)

typedef __attribute__((ext_vector_type(8))) short s16x8;
typedef __attribute__((ext_vector_type(4))) float f32x4;
typedef __attribute__((ext_vector_type(2))) float f32x2;

__device__ __forceinline__ unsigned short f2bf(float f) {
    unsigned u = __float_as_uint(f);
    return (unsigned short)((u + 0x7fff + ((u >> 16) & 1)) >> 16);
}

// ---------------- fp8 e4m3 encode/decode (HW path + sw fallback) ----------------
#if __has_builtin(__builtin_amdgcn_cvt_pk_fp8_f32) && __has_builtin(__builtin_amdgcn_cvt_pk_f32_fp8)
#define FP8_HW 1
#else
#define FP8_HW 0
#endif

__device__ __forceinline__ unsigned char f2fp8(float f) {
#if FP8_HW
    int v = __builtin_amdgcn_cvt_pk_fp8_f32(f, f, 0, false);
    return (unsigned char)(v & 0xff);
#else
    unsigned u = __float_as_uint(f);
    unsigned s = (u >> 24) & 0x80;
    float a = fabsf(f);
    if (a > 448.f) a = 448.f;
    if (a < 0.015625f) {
        int q = (int)(a * 512.f + 0.5f);
        return (unsigned char)(s | q);
    }
    unsigned ub = __float_as_uint(a);
    ub += 0x0007ffff + ((ub >> 20) & 1);
    int e8 = (int)(ub >> 23) - 127 + 7;
    if (e8 >= 16) return (unsigned char)(s | 0x7e);
    return (unsigned char)(s | (e8 << 3) | ((ub >> 20) & 7));
#endif
}

__device__ __forceinline__ void fp8acc4(unsigned w, float* acc) {
#if FP8_HW
    f32x2 lo = __builtin_amdgcn_cvt_pk_f32_fp8(w, false);
    f32x2 hi = __builtin_amdgcn_cvt_pk_f32_fp8(w, true);
    acc[0] += lo.x; acc[1] += lo.y; acc[2] += hi.x; acc[3] += hi.y;
#else
    #pragma unroll
    for (int j = 0; j < 4; ++j) {
        unsigned b = (w >> (8 * j)) & 0xff;
        unsigned s = (b >> 7) & 1, e = (b >> 3) & 15, m = b & 7;
        float v = e ? __uint_as_float(((e + 120) << 23) | (m << 20))
                    : (float)m * 0.001953125f;
        acc[j] += s ? -v : v;
    }
#endif
}

// ---------------- one-launch repack of all weights + uvc fold ----------------
__device__ __forceinline__ void repack_one(
    const float* __restrict__ W, short* __restrict__ Wp, int K, int t)
{
    int nkt = K >> 5;
    int lane = t & 63;
    int kt = (t >> 6) % nkt;
    int nt = (t >> 6) / nkt;
    int c = nt * 16 + (lane & 15);
    int kbase = kt * 32 + (lane >> 4) * 8;
    s16x8 v;
    #pragma unroll
    for (int j = 0; j < 8; ++j) v[j] = (short)f2bf(W[(long)(kbase + j) * HF + c]);
    *(s16x8*)(Wp + (long)t * 8) = v;
}

__global__ __launch_bounds__(256) void repack_all(
    const float* __restrict__ preW, const float* __restrict__ c1Ws,
    const float* __restrict__ c1Wn, const float* __restrict__ c2Ws,
    const float* __restrict__ c2Wn, const float* __restrict__ dW1,
    const float* __restrict__ dW2,
    short* preWp, short* c1Wsp, short* c1Wnp, short* c2Wsp, short* c2Wnp,
    short* dW1p, short* dW2p,
    const float* __restrict__ npW, const float* __restrict__ npb,
    const float* __restrict__ dW3, const float* __restrict__ db3,
    const float* __restrict__ fW,  const float* __restrict__ fb,
    float* __restrict__ uvc)
{
    int b = blockIdx.x;
    if (b == 64) {
        int i = threadIdx.x;
        if (i < HF) {
            float u = 0.f, v = 0.f;
            for (int j = 0; j < HF; ++j) {
                u += npW[i * HF + j] * fW[j];
                v += dW3[i * HF + j] * fW[HF + j];
            }
            uvc[i] = u;
            uvc[HF + i] = v;
            if (i == 0) {
                float c = fb[0];
                for (int j = 0; j < HF; ++j) c += npb[j] * fW[j] + db3[j] * fW[HF + j];
                uvc[2 * HF] = c;
            }
        }
        return;
    }
    if (b < 16) { repack_one(preW, preWp, 256, b * 256 + threadIdx.x); return; }
    int m = (b - 16) >> 3, t = ((b - 16) & 7) * 256 + threadIdx.x;
    const float* W; short* Wp;
    switch (m) {
        case 0: W = c1Ws; Wp = c1Wsp; break;
        case 1: W = c1Wn; Wp = c1Wnp; break;
        case 2: W = c2Ws; Wp = c2Wsp; break;
        case 3: W = c2Wn; Wp = c2Wnp; break;
        case 4: W = dW1;  Wp = dW1p;  break;
        default: W = dW2; Wp = dW2p;  break;
    }
    repack_one(W, Wp, HF, t);
}

// ---------------- bucket body: XCD-owned lines, single pass ----------
__device__ void bucket_body(
    int bb, const int* __restrict__ eidx, long E,
    int* __restrict__ deg, int* __restrict__ bucket, int npass)
{
    const int xcd   = bb & 7;
    const int chunk = bb >> 3;
    const int nchunks = BUCKET_BLOCKS / 8;
    long per = (E + nchunks - 1) / nchunks;
    per = (per + 3) & ~3L;
    const long e0 = (long)chunk * per;
    const long e1 = (e0 + per < E) ? e0 + per : E;
    if (e0 >= E) return;
    for (int p = 0; p < npass; ++p) {
        for (long e = e0 + (long)threadIdx.x * 4; e + 4 <= e1; e += 1024) {
            int4 d4 = *(const int4*)(eidx + E + e);
            #pragma unroll
            for (int j = 0; j < 4; ++j) {
                int d = (&d4.x)[j];
                if ((d >> PSHIFT) != p || ((d >> 4) & 7) != xcd) continue;
                int s = eidx[e + j];
                int pos = atomicAdd(&deg[d], 1);
                if (pos < CAP) bucket[(long)d * CAP + pos] = s;
            }
        }
        for (long e = (e1 & ~3L) + threadIdx.x; e < e1; e += 256) {
            int d = eidx[E + e];
            if ((d >> PSHIFT) != p || ((d >> 4) & 7) != xcd) continue;
            int s = eidx[e];
            int pos = atomicAdd(&deg[d], 1);
            if (pos < CAP) bucket[(long)d * CAP + pos] = s;
        }
    }
}

// ---------------- disthead body (256 thr, no LDS) ----------------
__device__ void disthead_body(int gb,
    const float* __restrict__ ea, const float* __restrict__ W0,
    const float* __restrict__ b0, const short* __restrict__ W1p,
    const float* __restrict__ b1, unsigned short* __restrict__ y1, int n)
{
    const int lane = threadIdx.x & 63;
    const int wv   = threadIdx.x >> 6;
    const long row0 = (long)gb * 64 + wv * 16;
    const int q = lane >> 4;
    long rA = row0 + (lane & 15);
    if (rA > n - 1) rA = n - 1;

    float e0 = ea[rA * 5 + 0], e1 = ea[rA * 5 + 1], e2 = ea[rA * 5 + 2],
          e3 = ea[rA * 5 + 3], e4 = ea[rA * 5 + 4];

    f32x4 acc[8];
    #pragma unroll
    for (int nt = 0; nt < 8; ++nt)
        #pragma unroll
        for (int i = 0; i < 4; ++i) acc[nt][i] = 0.f;

    #pragma unroll
    for (int kt = 0; kt < 4; ++kt) {
        const int c = kt * 32 + q * 8;
        s16x8 a;
        #pragma unroll
        for (int h = 0; h < 2; ++h) {
            float4 w0 = *(const float4*)(W0 + 0 * HF + c + h * 4);
            float4 w1 = *(const float4*)(W0 + 1 * HF + c + h * 4);
            float4 w2 = *(const float4*)(W0 + 2 * HF + c + h * 4);
            float4 w3v = *(const float4*)(W0 + 3 * HF + c + h * 4);
            float4 w4 = *(const float4*)(W0 + 4 * HF + c + h * 4);
            float4 bb = *(const float4*)(b0 + c + h * 4);
            float z0 = fmaxf(bb.x + e0 * w0.x + e1 * w1.x + e2 * w2.x + e3 * w3v.x + e4 * w4.x, 0.f);
            float z1 = fmaxf(bb.y + e0 * w0.y + e1 * w1.y + e2 * w2.y + e3 * w3v.y + e4 * w4.y, 0.f);
            float z2 = fmaxf(bb.z + e0 * w0.z + e1 * w1.z + e2 * w2.z + e3 * w3v.z + e4 * w4.z, 0.f);
            float z3 = fmaxf(bb.w + e0 * w0.w + e1 * w1.w + e2 * w2.w + e3 * w3v.w + e4 * w4.w, 0.f);
            a[h * 4 + 0] = (short)f2bf(z0); a[h * 4 + 1] = (short)f2bf(z1);
            a[h * 4 + 2] = (short)f2bf(z2); a[h * 4 + 3] = (short)f2bf(z3);
        }
        #pragma unroll
        for (int nt = 0; nt < 8; ++nt) {
            s16x8 b = *(const s16x8*)(W1p + ((long)(nt * 4 + kt) * 64 + lane) * 8);
            acc[nt] = __builtin_amdgcn_mfma_f32_16x16x32_bf16(a, b, acc[nt], 0, 0, 0);
        }
    }

    const int cq = lane >> 4;
    #pragma unroll
    for (int nt = 0; nt < 8; ++nt) {
        int col = nt * 16 + (lane & 15);
        float bs = b1[col];
        #pragma unroll
        for (int i = 0; i < 4; ++i) {
            long r = row0 + cq * 4 + i;
            if (r < n) y1[r * HF + col] = f2bf(fmaxf(acc[nt][i] + bs, 0.f));
        }
    }
}

// ---------------- megabd: bucketx || disthead, Bresenham-interleaved -------------
__global__ __launch_bounds__(256) void megabd_kernel(
    const int* __restrict__ eidx, long E,
    int* __restrict__ deg, int* __restrict__ bucket, int npass,
    const float* __restrict__ ea, const float* __restrict__ W0,
    const float* __restrict__ b0, const short* __restrict__ W1p,
    const float* __restrict__ b1, unsigned short* __restrict__ y1,
    int n, int total)
{
    const long bid = blockIdx.x;
    const long bcnt0 = (bid * BUCKET_BLOCKS) / total;
    const long bcnt1 = ((bid + 1) * BUCKET_BLOCKS) / total;
    if (bcnt1 > bcnt0) {
        bucket_body((int)bcnt0, eidx, E, deg, bucket, npass);
    } else {
        disthead_body((int)(bid - bcnt1), ea, W0, b0, W1p, b1, y1, n);
    }
}

// ---------------- bucket slice staging: predicated (skip chunks past deg) --------
__device__ __forceinline__ void stage_bucket(
    const int* __restrict__ bucket, const int* __restrict__ deg,
    long row0B, int n, int* ldsbkt, int* ldsdeg)
{
    if (threadIdx.x < 64) {
        long node = row0B + threadIdx.x;
        ldsdeg[threadIdx.x] = (node < n) ? deg[node] : 0;
    }
    const uint4* gb = (const uint4*)(bucket + row0B * CAP);
    #pragma unroll
    for (int h = 0; h < 2; ++h) {
        int u = threadIdx.x + h * 512;
        int row = u >> 4, q = u & 15;
        long node = row0B + row;
        int dgr = (node < n) ? deg[node] : 0;
        if (dgr > CAP) dgr = CAP;
        if (q * 4 < dgr)
            *(uint4*)&ldsbkt[row * BKS + q * 4] = gb[u];
    }
}

// ---------------- agg v2: 8 lanes/row x uint4, LDS indices, 8-deep MLP -----------
__device__ __forceinline__ void agg_tile_v2(
    const unsigned char* __restrict__ hq,
    const int* ldsbkt, const int* ldsdeg,
    int n, long row0B, int wv, int lane, unsigned* ldsagg)
{
    const int r = lane >> 3;
    const int i = lane & 7;
    const int rg = wv * 8 + r;

    const int dg = ldsdeg[rg];
    const int m  = dg < CAP ? dg : CAP;
    int maxm = m;
    maxm = max(maxm, __shfl_xor(maxm, 8, 64));
    maxm = max(maxm, __shfl_xor(maxm, 16, 64));
    maxm = max(maxm, __shfl_xor(maxm, 32, 64));

    float acc[16];
    #pragma unroll
    for (int j = 0; j < 16; ++j) acc[j] = 0.f;

    const int* bl = ldsbkt + rg * BKS;
    for (int e = 0; e < maxm; e += 8) {
        int4 ia = *(const int4*)(bl + e);
        int4 ib = *(const int4*)(bl + e + 4);
        int s0 = (e + 0 < m) ? ia.x : 0;
        int s1 = (e + 1 < m) ? ia.y : 0;
        int s2 = (e + 2 < m) ? ia.z : 0;
        int s3 = (e + 3 < m) ? ia.w : 0;
        int s4 = (e + 4 < m) ? ib.x : 0;
        int s5 = (e + 5 < m) ? ib.y : 0;
        int s6 = (e + 6 < m) ? ib.z : 0;
        int s7 = (e + 7 < m) ? ib.w : 0;
        uint4 v0 = *(const uint4*)(hq + (long)s0 * HF + i * 16);
        uint4 v1 = *(const uint4*)(hq + (long)s1 * HF + i * 16);
        uint4 v2 = *(const uint4*)(hq + (long)s2 * HF + i * 16);
        uint4 v3 = *(const uint4*)(hq + (long)s3 * HF + i * 16);
        uint4 v4 = *(const uint4*)(hq + (long)s4 * HF + i * 16);
        uint4 v5 = *(const uint4*)(hq + (long)s5 * HF + i * 16);
        uint4 v6 = *(const uint4*)(hq + (long)s6 * HF + i * 16);
        uint4 v7 = *(const uint4*)(hq + (long)s7 * HF + i * 16);
        if (e + 0 < m) { fp8acc4(v0.x, acc); fp8acc4(v0.y, acc + 4); fp8acc4(v0.z, acc + 8); fp8acc4(v0.w, acc + 12); }
        if (e + 1 < m) { fp8acc4(v1.x, acc); fp8acc4(v1.y, acc + 4); fp8acc4(v1.z, acc + 8); fp8acc4(v1.w, acc + 12); }
        if (e + 2 < m) { fp8acc4(v2.x, acc); fp8acc4(v2.y, acc + 4); fp8acc4(v2.z, acc + 8); fp8acc4(v2.w, acc + 12); }
        if (e + 3 < m) { fp8acc4(v3.x, acc); fp8acc4(v3.y, acc + 4); fp8acc4(v3.z, acc + 8); fp8acc4(v3.w, acc + 12); }
        if (e + 4 < m) { fp8acc4(v4.x, acc); fp8acc4(v4.y, acc + 4); fp8acc4(v4.z, acc + 8); fp8acc4(v4.w, acc + 12); }
        if (e + 5 < m) { fp8acc4(v5.x, acc); fp8acc4(v5.y, acc + 4); fp8acc4(v5.z, acc + 8); fp8acc4(v5.w, acc + 12); }
        if (e + 6 < m) { fp8acc4(v6.x, acc); fp8acc4(v6.y, acc + 4); fp8acc4(v6.z, acc + 8); fp8acc4(v6.w, acc + 12); }
        if (e + 7 < m) { fp8acc4(v7.x, acc); fp8acc4(v7.y, acc + 4); fp8acc4(v7.z, acc + 8); fp8acc4(v7.w, acc + 12); }
    }

    const float sc = 1.f / (float)(dg > 1 ? dg : 1);
    unsigned pk[8];
    #pragma unroll
    for (int j = 0; j < 8; ++j)
        pk[j] = (unsigned)f2bf(acc[2 * j] * sc) | ((unsigned)f2bf(acc[2 * j + 1] * sc) << 16);
    const int c0 = 2 * i, c1 = 2 * i + 1, s = rg & 15;
    *(uint4*)&ldsagg[rg * 64 + ((c0 ^ s) << 2)] = make_uint4(pk[0], pk[1], pk[2], pk[3]);
    *(uint4*)&ldsagg[rg * 64 + ((c1 ^ s) << 2)] = make_uint4(pk[4], pk[5], pk[6], pk[7]);
}

// ---------------- MFMA GEMM pass, A from global, 4-col-tile (N-split) ----------
__device__ __forceinline__ void gemm_pass4(
    const unsigned short* __restrict__ Av, const short* __restrict__ Wp,
    long rA, int lane, int nb, f32x4 acc[4])
{
    const int q = lane >> 4;
    #pragma unroll
    for (int kt = 0; kt < 4; ++kt) {
        s16x8 a = *(const s16x8*)(Av + rA * HF + kt * 32 + q * 8);
        #pragma unroll
        for (int j = 0; j < 4; ++j) {
            s16x8 b = *(const s16x8*)(Wp + ((long)((nb + j) * 4 + kt) * 64 + lane) * 8);
            acc[j] = __builtin_amdgcn_mfma_f32_16x16x32_bf16(a, b, acc[j], 0, 0, 0);
        }
    }
}

__device__ __forceinline__ void gemm_pass_lds4(
    const unsigned* lds, int w3, int lane, const short* __restrict__ Wp,
    int nb, f32x4 acc[4])
{
    const int q = lane >> 4;
    const int i15 = lane & 15;
    const int rl = w3 * 16 + i15;
    #pragma unroll
    for (int kt = 0; kt < 4; ++kt) {
        s16x8 a = *(const s16x8*)&lds[rl * 64 + (((kt * 4 + q) ^ i15) << 2)];
        #pragma unroll
        for (int j = 0; j < 4; ++j) {
            s16x8 b = *(const s16x8*)(Wp + ((long)((nb + j) * 4 + kt) * 64 + lane) * 8);
            acc[j] = __builtin_amdgcn_mfma_f32_16x16x32_bf16(a, b, acc[j], 0, 0, 0);
        }
    }
}

__device__ __forceinline__ void gemm_pass_mfma8(
    const unsigned short* __restrict__ Av, const short* __restrict__ Wp,
    long rA, int lane, f32x4 acc[8])
{
    const int q = lane >> 4;
    #pragma unroll
    for (int kt = 0; kt < 4; ++kt) {
        s16x8 a = *(const s16x8*)(Av + rA * HF + kt * 32 + q * 8);
        #pragma unroll
        for (int nt = 0; nt < 8; ++nt) {
            s16x8 b = *(const s16x8*)(Wp + ((long)(nt * 4 + kt) * 64 + lane) * 8);
            acc[nt] = __builtin_amdgcn_mfma_f32_16x16x32_bf16(a, b, acc[nt], 0, 0, 0);
        }
    }
}

__device__ __forceinline__ void gemm_pass_lds8(
    const unsigned* lds, int w3, int lane, const short* __restrict__ Wp, f32x4 acc[8])
{
    const int q = lane >> 4;
    const int i15 = lane & 15;
    const int rl = w3 * 16 + i15;
    #pragma unroll
    for (int kt = 0; kt < 4; ++kt) {
        s16x8 a = *(const s16x8*)&lds[rl * 64 + (((kt * 4 + q) ^ i15) << 2)];
        #pragma unroll
        for (int nt = 0; nt < 8; ++nt) {
            s16x8 b = *(const s16x8*)(Wp + ((long)(nt * 4 + kt) * 64 + lane) * 8);
            acc[nt] = __builtin_amdgcn_mfma_f32_16x16x32_bf16(a, b, acc[nt], 0, 0, 0);
        }
    }
}

// ---------------- prek v2 (512 thr): bf16 reg-staged x (32 KB LDS, conflict-free
//                  writes), 8-wave N-split GEMM, packed h0/h0q epilogue ----------
__global__ __launch_bounds__(512) void prek_kernel(
    const float* __restrict__ x, const short* __restrict__ preWp,
    const float* __restrict__ preb, unsigned short* __restrict__ h0,
    unsigned char* __restrict__ h0q, int n)
{
    __shared__ unsigned ldsx[64 * 128];   // 32 KB: 64 rows x 128 uints (256 bf16)
    const int lane = threadIdx.x & 63;
    const int wv   = threadIdx.x >> 6;
    const long row0B = (long)blockIdx.x * 64;

    // reg-stage: thread t -> row = t>>3; sub-lane j = t&7 owns chunks {j, 8+j, 16+j, 24+j}
    {
        const int t = threadIdx.x;
        const int row = t >> 3;
        const int j = t & 7;
        long rr = row0B + row;
        if (rr > n - 1) rr = n - 1;
        const float* xp = x + rr * 256;
        #pragma unroll
        for (int k = 0; k < 4; ++k) {
            const int c = k * 8 + j;                 // chunk = 4 uints = 8 bf16 cols
            float4 f0 = *(const float4*)(xp + c * 8);
            float4 f1 = *(const float4*)(xp + c * 8 + 4);
            uint4 v;
            v.x = (unsigned)f2bf(f0.x) | ((unsigned)f2bf(f0.y) << 16);
            v.y = (unsigned)f2bf(f0.z) | ((unsigned)f2bf(f0.w) << 16);
            v.z = (unsigned)f2bf(f1.x) | ((unsigned)f2bf(f1.y) << 16);
            v.w = (unsigned)f2bf(f1.z) | ((unsigned)f2bf(f1.w) << 16);
            const int phys = c ^ (row & 7);
            *(uint4*)&ldsx[row * 128 + phys * 4] = v;
        }
    }
    __syncthreads();

    const int w3 = wv & 3;
    const int nb = (wv >> 2) * 4;
    const int q  = lane >> 4;
    const int l15 = lane & 15;
    const int rl = w3 * 16 + l15;

    f32x4 acc[4];
    #pragma unroll
    for (int j = 0; j < 4; ++j)
        #pragma unroll
        for (int i = 0; i < 4; ++i) acc[j][i] = 0.f;

    #pragma unroll
    for (int kt = 0; kt < 8; ++kt) {
        const int c = kt * 4 + q;
        s16x8 a = *(const s16x8*)&ldsx[rl * 128 + ((c ^ (rl & 7)) << 2)];
        #pragma unroll
        for (int j = 0; j < 4; ++j) {
            s16x8 b = *(const s16x8*)(preWp + ((long)((nb + j) * 8 + kt) * 64 + lane) * 8);
            acc[j] = __builtin_amdgcn_mfma_f32_16x16x32_bf16(a, b, acc[j], 0, 0, 0);
        }
    }
    __syncthreads();   // ldsx free for pack tiles (24 KB used)

    unsigned short* lp16 = (unsigned short*)ldsx;
    unsigned char*  lp8  = (unsigned char*)ldsx + 16384;
    const int cq = lane >> 4;
    #pragma unroll
    for (int j = 0; j < 4; ++j) {
        int col = (nb + j) * 16 + l15;
        float bs = preb[col];
        #pragma unroll
        for (int i = 0; i < 4; ++i) {
            int row = w3 * 16 + cq * 4 + i;
            float o = acc[j][i] + bs;
            lp16[row * 128 + col] = f2bf(o);
            lp8[row * 128 + col]  = f2fp8(o);
        }
    }
    __syncthreads();

    const int r = threadIdx.x >> 3;
    const int c = (threadIdx.x & 7) * 16;
    const long gr = row0B + r;
    if (gr < n) {
        uint4* src = (uint4*)&lp16[r * 128 + c];
        *(uint4*)(h0 + gr * HF + c)     = src[0];
        *(uint4*)(h0 + gr * HF + c + 8) = src[1];
        *(uint4*)(h0q + gr * HF + c)    = *(uint4*)&lp8[r * 128 + c];
    }
}

// ---------------- c1f (512 thr): staged-bucket agg, then 8-wave N-split GEMM ------
__global__ __launch_bounds__(512) void c1f_kernel(
    const unsigned short* __restrict__ h0, const unsigned char* __restrict__ h0q,
    const int* __restrict__ deg, const int* __restrict__ bucket,
    const short* __restrict__ Wsp, const short* __restrict__ Wnp,
    const float* __restrict__ bias, unsigned short* __restrict__ out,
    unsigned char* __restrict__ outq, int n)
{
    __shared__ unsigned ldsagg[64 * 64];
    __shared__ int ldsbkt[64 * BKS];
    __shared__ int ldsdeg[64];
    const int lane = threadIdx.x & 63;
    const int wv   = threadIdx.x >> 6;
    const long row0B = (long)blockIdx.x * 64;

    stage_bucket(bucket, deg, row0B, n, ldsbkt, ldsdeg);
    __syncthreads();
    agg_tile_v2(h0q, ldsbkt, ldsdeg, n, row0B, wv, lane, ldsagg);
    __syncthreads();

    const int w3 = wv & 3;
    const int nb = (wv >> 2) * 4;

    f32x4 acc[4];
    #pragma unroll
    for (int j = 0; j < 4; ++j)
        #pragma unroll
        for (int i = 0; i < 4; ++i) acc[j][i] = 0.f;

    const long row0 = row0B + w3 * 16;
    long rA = row0 + (lane & 15);
    if (rA > n - 1) rA = n - 1;

    gemm_pass4(h0, Wsp, rA, lane, nb, acc);
    gemm_pass_lds4(ldsagg, w3, lane, Wnp, nb, acc);

    const int cq = lane >> 4;
    #pragma unroll
    for (int j = 0; j < 4; ++j) {
        int col = (nb + j) * 16 + (lane & 15);
        float bs = bias[col];
        #pragma unroll
        for (int i = 0; i < 4; ++i) {
            long r = row0 + cq * 4 + i;
            if (r < n) {
                float o = fmaxf(acc[j][i] + bs, 0.f);
                out[r * HF + col] = f2bf(o);
                outq[r * HF + col] = f2fp8(o);
            }
        }
    }
}

// ---------------- tailf (512 thr): staged-bucket agg; h waves 0-3 || y waves 4-7 --
__global__ __launch_bounds__(512) void tailf_kernel(
    const unsigned short* __restrict__ h1, const unsigned char* __restrict__ h1q,
    const unsigned short* __restrict__ y1,
    const int* __restrict__ deg, const int* __restrict__ bucket,
    const short* __restrict__ c2Wsp, const short* __restrict__ c2Wnp,
    const short* __restrict__ dW2p,
    const float* __restrict__ c2b, const float* __restrict__ db2,
    const float* __restrict__ uvc, float* __restrict__ out, int n)
{
    __shared__ unsigned ldsagg[64 * 64];
    __shared__ int ldsbkt[64 * BKS];
    __shared__ int ldsdeg[64];
    __shared__ float pp[2][64];
    const int lane = threadIdx.x & 63;
    const int wv   = threadIdx.x >> 6;
    const long row0B = (long)blockIdx.x * 64;

    stage_bucket(bucket, deg, row0B, n, ldsbkt, ldsdeg);
    __syncthreads();
    agg_tile_v2(h1q, ldsbkt, ldsdeg, n, row0B, wv, lane, ldsagg);
    __syncthreads();

    const int w = wv & 3;
    const long row0 = row0B + w * 16;
    long rA = row0 + (lane & 15);
    if (rA > n - 1) rA = n - 1;
    const int cq = lane >> 4;
    float part[4] = {0.f, 0.f, 0.f, 0.f};

    f32x4 acc[8];
    #pragma unroll
    for (int nt = 0; nt < 8; ++nt)
        #pragma unroll
        for (int i = 0; i < 4; ++i) acc[nt][i] = 0.f;

    if (wv < 4) {
        gemm_pass_mfma8(h1, c2Wsp, rA, lane, acc);
        gemm_pass_lds8(ldsagg, w, lane, c2Wnp, acc);
        #pragma unroll
        for (int nt = 0; nt < 8; ++nt) {
            int col = nt * 16 + (lane & 15);
            float bh = c2b[col], uu = uvc[col];
            #pragma unroll
            for (int i = 0; i < 4; ++i)
                part[i] += fmaxf(acc[nt][i] + bh, 0.f) * uu;
        }
    } else {
        gemm_pass_mfma8(y1, dW2p, rA, lane, acc);
        #pragma unroll
        for (int nt = 0; nt < 8; ++nt) {
            int col = nt * 16 + (lane & 15);
            float by = db2[col], vv = uvc[HF + col];
            #pragma unroll
            for (int i = 0; i < 4; ++i)
                part[i] += fmaxf(acc[nt][i] + by, 0.f) * vv;
        }
    }

    #pragma unroll
    for (int i = 0; i < 4; ++i) {
        float s = part[i];
        s += __shfl_xor(s, 1, 64);
        s += __shfl_xor(s, 2, 64);
        s += __shfl_xor(s, 4, 64);
        s += __shfl_xor(s, 8, 64);
        part[i] = s;
    }
    if ((lane & 15) == 0) {
        #pragma unroll
        for (int i = 0; i < 4; ++i)
            pp[wv >> 2][w * 16 + cq * 4 + i] = part[i];
    }
    __syncthreads();

    if (threadIdx.x < 64) {
        long r = row0B + threadIdx.x;
        if (r < n) {
            float s = pp[0][threadIdx.x] + pp[1][threadIdx.x] + uvc[2 * HF];
            out[r] = 1.f / (1.f + expf(-s));
        }
    }
}

extern "C" void kernel_launch(void* const* d_in, const int* in_sizes, int n_in,
                              void* d_out, int out_size, void* d_ws, size_t ws_size,
                              hipStream_t stream)
{
    const float* x      = (const float*)d_in[0];
    const int*   eidx   = (const int*)  d_in[1];
    const float* eattr  = (const float*)d_in[2];
    const float* pre_W  = (const float*)d_in[3];
    const float* pre_b  = (const float*)d_in[4];
    const float* c1_Ws  = (const float*)d_in[5];
    const float* c1_Wn  = (const float*)d_in[6];
    const float* c1_b   = (const float*)d_in[7];
    const float* c2_Ws  = (const float*)d_in[8];
    const float* c2_Wn  = (const float*)d_in[9];
    const float* c2_b   = (const float*)d_in[10];
    const float* npW    = (const float*)d_in[11];
    const float* npb    = (const float*)d_in[12];
    const float* dW0    = (const float*)d_in[13];
    const float* db0    = (const float*)d_in[14];
    const float* dW1    = (const float*)d_in[15];
    const float* db1    = (const float*)d_in[16];
    const float* dW2    = (const float*)d_in[17];
    const float* db2    = (const float*)d_in[18];
    const float* dW3    = (const float*)d_in[19];
    const float* db3    = (const float*)d_in[20];
    const float* fW     = (const float*)d_in[21];
    const float* fb     = (const float*)d_in[22];

    const int  n = in_sizes[0] / 256;
    const long E = in_sizes[1] / 2;

    char* ws = (char*)d_ws;
    size_t off = 0;
    auto alloc = [&](size_t bytes) -> void* {
        void* p = ws + off;
        off += (bytes + 255) & ~(size_t)255;
        return p;
    };
    unsigned short* B0 = (unsigned short*)alloc((size_t)n * HF * 2); // h0
    unsigned short* B1 = (unsigned short*)alloc((size_t)n * HF * 2); // h1
    unsigned short* B2 = (unsigned short*)alloc((size_t)n * HF * 2); // y1
    unsigned char*  B0q = (unsigned char*)alloc((size_t)n * HF);    // h0 fp8
    unsigned char*  B1q = (unsigned char*)alloc((size_t)n * HF);    // h1 fp8
    int*   deg    = (int*)alloc((size_t)n * sizeof(int));
    int*   bucket = (int*)alloc(((size_t)n + 64) * CAP * sizeof(int));
    float* uvc    = (float*)alloc((2 * HF + 1) * sizeof(float));
    short* preWp  = (short*)alloc(256 * HF * 2);
    short* c1Wsp  = (short*)alloc(HF * HF * 2);
    short* c1Wnp  = (short*)alloc(HF * HF * 2);
    short* c2Wsp  = (short*)alloc(HF * HF * 2);
    short* c2Wnp  = (short*)alloc(HF * HF * 2);
    short* dW1p   = (short*)alloc(HF * HF * 2);
    short* dW2p   = (short*)alloc(HF * HF * 2);

    const int gemmBlocks = (n + 63) / 64;
    const int npass = ((n - 1) >> PSHIFT) + 1;   // 1 at N=100k

    repack_all<<<65, 256, 0, stream>>>(
        pre_W, c1_Ws, c1_Wn, c2_Ws, c2_Wn, dW1, dW2,
        preWp, c1Wsp, c1Wnp, c2Wsp, c2Wnp, dW1p, dW2p,
        npW, npb, dW3, db3, fW, fb, uvc);

    hipMemsetAsync(deg, 0, (size_t)n * sizeof(int), stream);

    // bucket scatter || dist head, Bresenham-interleaved for CU co-residency
    const int total = BUCKET_BLOCKS + gemmBlocks;
    megabd_kernel<<<total, 256, 0, stream>>>(
        eidx, E, deg, bucket, npass,
        eattr, dW0, db0, dW1p, db1, B2,
        n, total);

    // h0 = x @ pre_W + pre_b : bf16 reg-staged GEMM (32 KB LDS, 4 blocks/CU)
    prek_kernel<<<gemmBlocks, 512, 0, stream>>>(x, preWp, pre_b, B0, B0q, n);

    // h1 = relu(h0@c1Ws + agg1@c1Wn + b): predicated-staged indices + wide gather
    c1f_kernel<<<gemmBlocks, 512, 0, stream>>>(
        B0, B0q, deg, bucket, c1Wsp, c1Wnp, c1_b, B1, B1q, n);

    // tail: staged agg2 + parallel h/y GEMM paths + final dot + sigmoid
    tailf_kernel<<<gemmBlocks, 512, 0, stream>>>(
        B1, B1q, B2, deg, bucket, c2Wsp, c2Wnp, dW2p, c2_b, db2, uvc, (float*)d_out, n);
}